// Round 1
// baseline (600.124 us; speedup 1.0000x reference)
//
#include <hip/hip_runtime.h>
#include <hip/hip_bf16.h>

#define NTOK 8192   // B*T
#define DM   1024
#define TT   2048
#define NH   16
#define DEPTH 64

typedef __hip_bfloat16 bf16;
typedef short bf16x8 __attribute__((ext_vector_type(8)));
typedef float f32x4  __attribute__((ext_vector_type(4)));

__device__ __forceinline__ void gload_lds16(const void* g, void* l) {
  __builtin_amdgcn_global_load_lds(
      (const __attribute__((address_space(1))) unsigned int*)g,
      (__attribute__((address_space(3))) unsigned int*)l, 16, 0, 0);
}

// ---------------- fp32 -> bf16 conversion (vectorized) ----------------
__global__ void cvt_k(const float* __restrict__ src, bf16* __restrict__ dst, int n4) {
  int i = blockIdx.x * 256 + threadIdx.x;
  if (i >= n4) return;
  float4 v = reinterpret_cast<const float4*>(src)[i];
  bf16 o[4] = {__float2bfloat16(v.x), __float2bfloat16(v.y),
               __float2bfloat16(v.z), __float2bfloat16(v.w)};
  reinterpret_cast<ushort4*>(dst)[i] = *reinterpret_cast<ushort4*>(o);
}

// ---------------- ones for output 0 (softmax over size-1 axis) ----------------
__global__ void ones_k(float* __restrict__ out) {
  out[blockIdx.x * 256 + threadIdx.x] = 1.0f;
}

// ---------------- C = (A @ W^T + bias) * scale, bf16 in/out ----------------
// A:[M,K] bf16, W:[N,K] bf16, bias:[N] f32, C:[M,N] bf16.  128x128 tile, BK=64.
__global__ void gemm_bt(const bf16* __restrict__ A, const bf16* __restrict__ W,
                        const float* __restrict__ bias, bf16* __restrict__ C,
                        int M, int N, int K, float scale)
{
  __shared__ bf16 sA[128 * 64];
  __shared__ bf16 sB[128 * 64];
  const int tid  = threadIdx.x;
  const int lane = tid & 63;
  const int wave = tid >> 6;
  const int ntn  = N >> 7;
  const int bm   = (blockIdx.x / ntn) << 7;
  const int bn   = (blockIdx.x % ntn) << 7;
  const int wr   = (wave >> 1) << 6;   // 0 or 64
  const int wc   = (wave & 1) << 6;    // 0 or 64
  const int lrow = lane & 15;
  const int lk8  = (lane >> 4) << 3;

  const int trow = tid >> 3;           // 0..31
  const int tcol = (tid & 7) << 3;     // 0,8,..,56

  f32x4 acc[4][4] = {};

  for (int k0 = 0; k0 < K; k0 += 64) {
#pragma unroll
    for (int i = 0; i < 4; ++i) {
      const int r = trow + i * 32;
      gload_lds16(A + (size_t)(bm + r) * K + k0 + tcol, sA + r * 64 + tcol);
      gload_lds16(W + (size_t)(bn + r) * K + k0 + tcol, sB + r * 64 + tcol);
    }
    __syncthreads();

    bf16x8 af[4][2], bfr[4][2];
#pragma unroll
    for (int mi = 0; mi < 4; ++mi) {
      af[mi][0]  = *reinterpret_cast<const bf16x8*>(sA + (wr + mi * 16 + lrow) * 64 + lk8);
      af[mi][1]  = *reinterpret_cast<const bf16x8*>(sA + (wr + mi * 16 + lrow) * 64 + 32 + lk8);
      bfr[mi][0] = *reinterpret_cast<const bf16x8*>(sB + (wc + mi * 16 + lrow) * 64 + lk8);
      bfr[mi][1] = *reinterpret_cast<const bf16x8*>(sB + (wc + mi * 16 + lrow) * 64 + 32 + lk8);
    }
#pragma unroll
    for (int mi = 0; mi < 4; ++mi)
#pragma unroll
      for (int ni = 0; ni < 4; ++ni) {
        acc[mi][ni] = __builtin_amdgcn_mfma_f32_16x16x32_bf16(af[mi][0], bfr[ni][0], acc[mi][ni], 0, 0, 0);
        acc[mi][ni] = __builtin_amdgcn_mfma_f32_16x16x32_bf16(af[mi][1], bfr[ni][1], acc[mi][ni], 0, 0, 0);
      }
    __syncthreads();
  }

#pragma unroll
  for (int mi = 0; mi < 4; ++mi)
#pragma unroll
    for (int ni = 0; ni < 4; ++ni) {
      const int col = bn + wc + ni * 16 + lrow;
      const float bv = bias[col];
#pragma unroll
      for (int j = 0; j < 4; ++j) {
        const int row = bm + wr + mi * 16 + ((lane >> 4) << 2) + j;
        C[(size_t)row * N + col] = __float2bfloat16((acc[mi][ni][j] + bv) * scale);
      }
    }
}

// ---------------- fused QK^T + softmax, writes attn [B,H,T,T] fp32 ----------------
// Q was pre-scaled by log2(e)/8, so softmax uses exp2 directly.
// Block: 256 thr (4 waves), q-tile = 128 rows (32/wave). grid (TT/128, B*NH).
__global__ __launch_bounds__(256, 4) void attn_k(
    const bf16* __restrict__ Qp, const bf16* __restrict__ Kp, float* __restrict__ attn)
{
  const int tid  = threadIdx.x;
  const int lane = tid & 63;
  const int wave = tid >> 6;
  const int qt   = blockIdx.x;       // 0..15
  const int bh   = blockIdx.y;       // 0..63
  const int b    = bh >> 4;
  const int h    = bh & 15;
  const int q0   = qt * 128 + wave * 32;
  const int lrow = lane & 15;
  const int lk8  = (lane >> 4) << 3;

  bf16x8 aq[2][2];
#pragma unroll
  for (int mi = 0; mi < 2; ++mi) {
    const bf16* qptr = Qp + (size_t)(b * TT + q0 + mi * 16 + lrow) * DM + h * DEPTH + lk8;
    aq[mi][0] = *reinterpret_cast<const bf16x8*>(qptr);
    aq[mi][1] = *reinterpret_cast<const bf16x8*>(qptr + 32);
  }

  const bf16* kbase = Kp + (size_t)(b * TT + lrow) * DM + h * DEPTH + lk8;

  float m[8], s[8];
#pragma unroll
  for (int i = 0; i < 8; ++i) { m[i] = -__builtin_inff(); s[i] = 0.0f; }

  // ---- pass 1: online row max + sum of exp2 ----
  for (int n0 = 0; n0 < TT; n0 += 16) {
    const bf16* kp = kbase + (size_t)n0 * DM;
    bf16x8 bk0 = *reinterpret_cast<const bf16x8*>(kp);
    bf16x8 bk1 = *reinterpret_cast<const bf16x8*>(kp + 32);
#pragma unroll
    for (int mi = 0; mi < 2; ++mi) {
      f32x4 acc = {0.f, 0.f, 0.f, 0.f};
      acc = __builtin_amdgcn_mfma_f32_16x16x32_bf16(aq[mi][0], bk0, acc, 0, 0, 0);
      acc = __builtin_amdgcn_mfma_f32_16x16x32_bf16(aq[mi][1], bk1, acc, 0, 0, 0);
#pragma unroll
      for (int r = 0; r < 4; ++r) {
        const float v  = acc[r];
        const int   ix = mi * 4 + r;
        const float mn = fmaxf(m[ix], v);
        s[ix] = s[ix] * __builtin_amdgcn_exp2f(m[ix] - mn) + __builtin_amdgcn_exp2f(v - mn);
        m[ix] = mn;
      }
    }
  }

  // ---- merge partials across the 16 lanes sharing each row ----
  float inv[8];
#pragma unroll
  for (int i = 0; i < 8; ++i) {
    float mr = m[i], sr = s[i];
#pragma unroll
    for (int off = 1; off < 16; off <<= 1) {
      const float mo = __shfl_xor(mr, off);
      const float so = __shfl_xor(sr, off);
      const float mn = fmaxf(mr, mo);
      sr = sr * __builtin_amdgcn_exp2f(mr - mn) + so * __builtin_amdgcn_exp2f(mo - mn);
      mr = mn;
    }
    m[i]   = mr;
    inv[i] = 1.0f / sr;
  }

  // ---- pass 2: recompute S, write normalized softmax ----
  float* obase = attn + ((size_t)bh * TT + q0 + ((lane >> 4) << 2)) * TT + lrow;

  for (int n0 = 0; n0 < TT; n0 += 16) {
    const bf16* kp = kbase + (size_t)n0 * DM;
    bf16x8 bk0 = *reinterpret_cast<const bf16x8*>(kp);
    bf16x8 bk1 = *reinterpret_cast<const bf16x8*>(kp + 32);
#pragma unroll
    for (int mi = 0; mi < 2; ++mi) {
      f32x4 acc = {0.f, 0.f, 0.f, 0.f};
      acc = __builtin_amdgcn_mfma_f32_16x16x32_bf16(aq[mi][0], bk0, acc, 0, 0, 0);
      acc = __builtin_amdgcn_mfma_f32_16x16x32_bf16(aq[mi][1], bk1, acc, 0, 0, 0);
#pragma unroll
      for (int r = 0; r < 4; ++r) {
        const int   ix = mi * 4 + r;
        const float p  = __builtin_amdgcn_exp2f(acc[r] - m[ix]) * inv[ix];
        __builtin_nontemporal_store(p, obase + (size_t)(mi * 16 + r) * TT + n0);
      }
    }
  }
}

extern "C" void kernel_launch(void* const* d_in, const int* in_sizes, int n_in,
                              void* d_out, int out_size, void* d_ws, size_t ws_size,
                              hipStream_t stream) {
  // setup_inputs order: v,k,q, wq_w,wq_b, wk_w,wk_b, wv_w,wv_b, dense_w,dense_b, fc_w,fc_b
  const float* k_in  = (const float*)d_in[1];
  const float* q_in  = (const float*)d_in[2];
  const float* wq_w  = (const float*)d_in[3];
  const float* wq_b  = (const float*)d_in[4];
  const float* wk_w  = (const float*)d_in[5];
  const float* wk_b  = (const float*)d_in[6];
  float* out = (float*)d_out;

  // workspace layout (bf16): qbf,kbf [8192x1024], wqbf,wkbf [1024x1024], Qp,Kp [8192x1024]
  bf16* qbf  = (bf16*)d_ws;
  bf16* kbf  = qbf  + (size_t)NTOK * DM;
  bf16* wqbf = kbf  + (size_t)NTOK * DM;
  bf16* wkbf = wqbf + (size_t)DM * DM;
  bf16* Qp   = wkbf + (size_t)DM * DM;
  bf16* Kp   = Qp   + (size_t)NTOK * DM;

  const int n4_qk = NTOK * DM / 4;   // 2,097,152
  const int n4_w  = DM * DM / 4;     // 262,144
  cvt_k<<<n4_qk / 256, 256, 0, stream>>>(q_in, qbf, n4_qk);
  cvt_k<<<n4_qk / 256, 256, 0, stream>>>(k_in, kbf, n4_qk);
  cvt_k<<<n4_w / 256, 256, 0, stream>>>(wq_w, wqbf, n4_w);
  cvt_k<<<n4_w / 256, 256, 0, stream>>>(wk_w, wkbf, n4_w);

  const float kScaleQ = 0.18033688011112042f;  // log2(e) / sqrt(64)
  const int gemm_blocks = (NTOK / 128) * (DM / 128);  // 512
  gemm_bt<<<gemm_blocks, 256, 0, stream>>>(qbf, wqbf, wq_b, Qp, NTOK, DM, DM, kScaleQ);
  gemm_bt<<<gemm_blocks, 256, 0, stream>>>(kbf, wkbf, wk_b, Kp, NTOK, DM, DM, 1.0f);

  ones_k<<<32, 256, 0, stream>>>(out);

  dim3 ag(TT / 128, 4 * NH);
  attn_k<<<ag, 256, 0, stream>>>(Qp, Kp, out + 8192);
}

// Round 2
// 465.862 us; speedup vs baseline: 1.2882x; 1.2882x over previous
//
#include <hip/hip_runtime.h>
#include <hip/hip_bf16.h>

#define NTOK 8192   // B*T
#define DM   1024
#define TT   2048
#define NH   16

typedef __hip_bfloat16 bf16;
typedef short bf16x8 __attribute__((ext_vector_type(8)));
typedef float f32x4  __attribute__((ext_vector_type(4)));
typedef float f32x16 __attribute__((ext_vector_type(16)));

#define N4_QK 2097152   // 8192*1024/4
#define N4_W  262144    // 1024*1024/4
#define N4_ONES 2048    // 8192/4

__device__ __forceinline__ void gload_lds16(const void* g, void* l) {
  __builtin_amdgcn_global_load_lds(
      (const __attribute__((address_space(1))) unsigned int*)g,
      (__attribute__((address_space(3))) unsigned int*)l, 16, 0, 0);
}

// ---- fused fp32->bf16 cvt (q,k,wq,wk -> contiguous bf16 ws) + ones for out0 ----
__global__ void prep_k(const float* __restrict__ q, const float* __restrict__ k,
                       const float* __restrict__ wq, const float* __restrict__ wk,
                       bf16* __restrict__ dst, float* __restrict__ ones) {
  const int i = blockIdx.x * 256 + threadIdx.x;
  const int total_cvt = 2 * N4_QK + 2 * N4_W;
  if (i < total_cvt) {
    const float* src;
    if (i < N4_QK)            src = q  + (size_t)i * 4;
    else if (i < 2 * N4_QK)   src = k  + (size_t)(i - N4_QK) * 4;
    else if (i < 2 * N4_QK + N4_W) src = wq + (size_t)(i - 2 * N4_QK) * 4;
    else                      src = wk + (size_t)(i - 2 * N4_QK - N4_W) * 4;
    float4 v = *reinterpret_cast<const float4*>(src);
    bf16 o[4] = {__float2bfloat16(v.x), __float2bfloat16(v.y),
                 __float2bfloat16(v.z), __float2bfloat16(v.w)};
    reinterpret_cast<ushort4*>(dst)[i] = *reinterpret_cast<ushort4*>(o);
  } else {
    const int j = i - total_cvt;          // 0..2047
    reinterpret_cast<float4*>(ones)[j] = make_float4(1.f, 1.f, 1.f, 1.f);
  }
}

// ---- merged projection GEMM: C[8192][2048] = [ (q@wq^T+bq)*log2e/8 | k@wk^T+bk ] ----
// Aq,Ak:[8192,1024] bf16, W:[2048,1024] bf16 (wq rows then wk rows), C bf16 stride 2048.
__global__ void gemm_qk(const bf16* __restrict__ Aq, const bf16* __restrict__ Ak,
                        const bf16* __restrict__ W,
                        const float* __restrict__ bq, const float* __restrict__ bk,
                        bf16* __restrict__ C)
{
  __shared__ bf16 sA[128 * 64];
  __shared__ bf16 sB[128 * 64];
  const int tid  = threadIdx.x;
  const int lane = tid & 63;
  const int wave = tid >> 6;
  const int bm   = (blockIdx.x >> 4) << 7;   // /16 n-tiles
  const int bn   = (blockIdx.x & 15) << 7;
  const bool isQ = bn < 1024;
  const bf16* __restrict__ A = isQ ? Aq : Ak;
  const float scale = isQ ? 0.18033688011112042f : 1.0f;  // log2(e)/8
  const float* __restrict__ bias = isQ ? bq : (bk - 1024);

  const int wr   = (wave >> 1) << 6;
  const int wc   = (wave & 1) << 6;
  const int lrow = lane & 15;
  const int lk8  = (lane >> 4) << 3;
  const int trow = tid >> 3;
  const int tcol = (tid & 7) << 3;

  f32x4 acc[4][4] = {};

  for (int k0 = 0; k0 < 1024; k0 += 64) {
#pragma unroll
    for (int i = 0; i < 4; ++i) {
      const int r = trow + i * 32;
      gload_lds16(A + (size_t)(bm + r) * 1024 + k0 + tcol, sA + r * 64 + tcol);
      gload_lds16(W + (size_t)(bn + r) * 1024 + k0 + tcol, sB + r * 64 + tcol);
    }
    __syncthreads();

    bf16x8 af[4][2], bfr[4][2];
#pragma unroll
    for (int mi = 0; mi < 4; ++mi) {
      af[mi][0]  = *reinterpret_cast<const bf16x8*>(sA + (wr + mi * 16 + lrow) * 64 + lk8);
      af[mi][1]  = *reinterpret_cast<const bf16x8*>(sA + (wr + mi * 16 + lrow) * 64 + 32 + lk8);
      bfr[mi][0] = *reinterpret_cast<const bf16x8*>(sB + (wc + mi * 16 + lrow) * 64 + lk8);
      bfr[mi][1] = *reinterpret_cast<const bf16x8*>(sB + (wc + mi * 16 + lrow) * 64 + 32 + lk8);
    }
#pragma unroll
    for (int mi = 0; mi < 4; ++mi)
#pragma unroll
      for (int ni = 0; ni < 4; ++ni) {
        acc[mi][ni] = __builtin_amdgcn_mfma_f32_16x16x32_bf16(af[mi][0], bfr[ni][0], acc[mi][ni], 0, 0, 0);
        acc[mi][ni] = __builtin_amdgcn_mfma_f32_16x16x32_bf16(af[mi][1], bfr[ni][1], acc[mi][ni], 0, 0, 0);
      }
    __syncthreads();
  }

#pragma unroll
  for (int mi = 0; mi < 4; ++mi)
#pragma unroll
    for (int ni = 0; ni < 4; ++ni) {
      const int col = bn + wc + ni * 16 + lrow;
      const float bv = bias[col];
#pragma unroll
      for (int j = 0; j < 4; ++j) {
        const int row = bm + wr + mi * 16 + ((lane >> 4) << 2) + j;
        C[(size_t)row * 2048 + col] = __float2bfloat16((acc[mi][ni][j] + bv) * scale);
      }
    }
}

// ---- fused QK^T + softmax (no-max, shift-invariant), 32x32 MFMA ----
// QK:[8192,2048] bf16 (Q cols 0..1023 prescaled by log2e/8, K cols 1024..2047).
// grid (16, 64): x = q-tile of 128 rows (32/wave), y = b*16+h.
__global__ __launch_bounds__(256, 4) void attn2_k(
    const bf16* __restrict__ QK, float* __restrict__ attn)
{
  const int tid  = threadIdx.x;
  const int lane = tid & 63;
  const int wave = tid >> 6;
  const int l31  = lane & 31;
  const int lh   = lane >> 5;
  const int bh   = blockIdx.y;       // b*16+h
  const int b    = bh >> 4;
  const int h    = bh & 15;
  const int q0   = blockIdx.x * 128 + wave * 32;

  // A fragment (Q): row = l31, k = lh*8 + j (+16 per chunk t)
  const bf16* qbase = QK + (size_t)(b * TT + q0 + l31) * 2048 + h * 64 + lh * 8;
  bf16x8 aq[4];
#pragma unroll
  for (int t = 0; t < 4; ++t)
    aq[t] = *reinterpret_cast<const bf16x8*>(qbase + t * 16);

  // B fragment (K^T): col = token = n0 + l31, k = d = lh*8 + j (+16 per chunk t)
  const bf16* kbase = QK + (size_t)(b * TT + l31) * 2048 + 1024 + h * 64 + lh * 8;

  float s[16];
#pragma unroll
  for (int r = 0; r < 16; ++r) s[r] = 0.f;

  // ---- pass 1: row sums of exp2(S) ----
  for (int n0 = 0; n0 < TT; n0 += 32) {
    const bf16* kp = kbase + (size_t)n0 * 2048;
    bf16x8 bk0 = *reinterpret_cast<const bf16x8*>(kp);
    bf16x8 bk1 = *reinterpret_cast<const bf16x8*>(kp + 16);
    bf16x8 bk2 = *reinterpret_cast<const bf16x8*>(kp + 32);
    bf16x8 bk3 = *reinterpret_cast<const bf16x8*>(kp + 48);
    f32x16 acc = {};
    acc = __builtin_amdgcn_mfma_f32_32x32x16_bf16(aq[0], bk0, acc, 0, 0, 0);
    acc = __builtin_amdgcn_mfma_f32_32x32x16_bf16(aq[1], bk1, acc, 0, 0, 0);
    acc = __builtin_amdgcn_mfma_f32_32x32x16_bf16(aq[2], bk2, acc, 0, 0, 0);
    acc = __builtin_amdgcn_mfma_f32_32x32x16_bf16(aq[3], bk3, acc, 0, 0, 0);
#pragma unroll
    for (int r = 0; r < 16; ++r) s[r] += __builtin_amdgcn_exp2f(acc[r]);
  }

  // ---- merge partial sums across the 32 lanes sharing each row; invert ----
#pragma unroll
  for (int r = 0; r < 16; ++r) {
    float sr = s[r];
    sr += __shfl_xor(sr, 1);
    sr += __shfl_xor(sr, 2);
    sr += __shfl_xor(sr, 4);
    sr += __shfl_xor(sr, 8);
    sr += __shfl_xor(sr, 16);
    s[r] = 1.0f / sr;
  }

  // D layout: col = n0 + l31, row = q0 + (r&3) + 8*(r>>2) + 4*lh
  float* obase = attn + ((size_t)bh * TT + q0 + 4 * lh) * TT + l31;

  // ---- pass 2: recompute S, write normalized softmax ----
  for (int n0 = 0; n0 < TT; n0 += 32) {
    const bf16* kp = kbase + (size_t)n0 * 2048;
    bf16x8 bk0 = *reinterpret_cast<const bf16x8*>(kp);
    bf16x8 bk1 = *reinterpret_cast<const bf16x8*>(kp + 16);
    bf16x8 bk2 = *reinterpret_cast<const bf16x8*>(kp + 32);
    bf16x8 bk3 = *reinterpret_cast<const bf16x8*>(kp + 48);
    f32x16 acc = {};
    acc = __builtin_amdgcn_mfma_f32_32x32x16_bf16(aq[0], bk0, acc, 0, 0, 0);
    acc = __builtin_amdgcn_mfma_f32_32x32x16_bf16(aq[1], bk1, acc, 0, 0, 0);
    acc = __builtin_amdgcn_mfma_f32_32x32x16_bf16(aq[2], bk2, acc, 0, 0, 0);
    acc = __builtin_amdgcn_mfma_f32_32x32x16_bf16(aq[3], bk3, acc, 0, 0, 0);
#pragma unroll
    for (int r = 0; r < 16; ++r) {
      const float p = __builtin_amdgcn_exp2f(acc[r]) * s[r];
      __builtin_nontemporal_store(p, obase + (size_t)((r & 3) + 8 * (r >> 2)) * TT + n0);
    }
  }
}

extern "C" void kernel_launch(void* const* d_in, const int* in_sizes, int n_in,
                              void* d_out, int out_size, void* d_ws, size_t ws_size,
                              hipStream_t stream) {
  // inputs: v,k,q, wq_w,wq_b, wk_w,wk_b, wv_w,wv_b, dense_w,dense_b, fc_w,fc_b
  const float* k_in = (const float*)d_in[1];
  const float* q_in = (const float*)d_in[2];
  const float* wq_w = (const float*)d_in[3];
  const float* wq_b = (const float*)d_in[4];
  const float* wk_w = (const float*)d_in[5];
  const float* wk_b = (const float*)d_in[6];
  float* out = (float*)d_out;

  // ws layout (bf16, contiguous cvt dst): qbf,kbf [8192x1024], wqbf+wkbf [2048x1024], QKp [8192x2048]
  bf16* qbf  = (bf16*)d_ws;
  bf16* kbf  = qbf  + (size_t)NTOK * DM;
  bf16* w2   = kbf  + (size_t)NTOK * DM;     // wq rows then wk rows
  bf16* QKp  = w2   + (size_t)2 * DM * DM;

  const int prep_blocks = (2 * N4_QK + 2 * N4_W + N4_ONES) / 256;  // 18440
  prep_k<<<prep_blocks, 256, 0, stream>>>(q_in, k_in, wq_w, wk_w, qbf, out);

  gemm_qk<<<1024, 256, 0, stream>>>(qbf, kbf, w2, wq_b, wk_b, QKp);

  dim3 ag(TT / 128, 4 * NH);
  attn2_k<<<ag, 256, 0, stream>>>(QKp, out + 8192);
}

// Round 3
// 364.969 us; speedup vs baseline: 1.6443x; 1.2764x over previous
//
#include <hip/hip_runtime.h>
#include <hip/hip_bf16.h>

#define NTOK 8192   // B*T
#define DM   1024
#define TT   2048
#define NH   16
#define BH_STRIDE (TT * 64)   // 131072 elems per (b,h) in permuted Q/K

typedef __hip_bfloat16 bf16;
typedef short bf16x8 __attribute__((ext_vector_type(8)));
typedef float f32x4  __attribute__((ext_vector_type(4)));
typedef float f32x16 __attribute__((ext_vector_type(16)));

#define N4_QK 2097152   // 8192*1024/4
#define N4_W  262144    // 1024*1024/4
#define N4_ONES 2048    // 8192/4

__device__ __forceinline__ void gload_lds16(const void* g, void* l) {
  __builtin_amdgcn_global_load_lds(
      (const __attribute__((address_space(1))) unsigned int*)g,
      (__attribute__((address_space(3))) unsigned int*)l, 16, 0, 0);
}

// ---- fused fp32->bf16 cvt (q,k,wq,wk -> contiguous bf16 ws) + ones for out0 ----
__global__ void prep_k(const float* __restrict__ q, const float* __restrict__ k,
                       const float* __restrict__ wq, const float* __restrict__ wk,
                       bf16* __restrict__ dst, float* __restrict__ ones) {
  const int i = blockIdx.x * 256 + threadIdx.x;
  const int total_cvt = 2 * N4_QK + 2 * N4_W;
  if (i < total_cvt) {
    const float* src;
    if (i < N4_QK)            src = q  + (size_t)i * 4;
    else if (i < 2 * N4_QK)   src = k  + (size_t)(i - N4_QK) * 4;
    else if (i < 2 * N4_QK + N4_W) src = wq + (size_t)(i - 2 * N4_QK) * 4;
    else                      src = wk + (size_t)(i - 2 * N4_QK - N4_W) * 4;
    float4 v = *reinterpret_cast<const float4*>(src);
    bf16 o[4] = {__float2bfloat16(v.x), __float2bfloat16(v.y),
                 __float2bfloat16(v.z), __float2bfloat16(v.w)};
    reinterpret_cast<ushort4*>(dst)[i] = *reinterpret_cast<ushort4*>(o);
  } else {
    const int j = i - total_cvt;          // 0..2047
    reinterpret_cast<float4*>(ones)[j] = make_float4(1.f, 1.f, 1.f, 1.f);
  }
}

// ---- merged projection GEMM, epilogue writes PERMUTED fragment-native layout ----
// Qp/Kp[(b*16+h)][tc(64)][t(4)][lh(2)][tk(32)][e(8)]: element (tok,d) at
// tc=tok>>5, tk=tok&31, t=d>>4, lh=(d>>3)&1, e=d&7.
__global__ void gemm_qk(const bf16* __restrict__ Aq, const bf16* __restrict__ Ak,
                        const bf16* __restrict__ W,
                        const float* __restrict__ bq, const float* __restrict__ bk,
                        bf16* __restrict__ Qp, bf16* __restrict__ Kp)
{
  __shared__ bf16 sA[128 * 64];
  __shared__ bf16 sB[128 * 64];
  const int tid  = threadIdx.x;
  const int lane = tid & 63;
  const int wave = tid >> 6;
  const int bm   = (blockIdx.x >> 4) << 7;
  const int bn   = (blockIdx.x & 15) << 7;
  const bool isQ = bn < 1024;
  const bf16* __restrict__ A = isQ ? Aq : Ak;
  const float scale = isQ ? 0.18033688011112042f : 1.0f;  // log2(e)/8
  const float* __restrict__ bias = isQ ? bq : (bk - 1024);
  bf16* __restrict__ dst = isQ ? Qp : Kp;

  const int wr   = (wave >> 1) << 6;
  const int wc   = (wave & 1) << 6;
  const int lrow = lane & 15;
  const int lk8  = (lane >> 4) << 3;
  const int trow = tid >> 3;
  const int tcol = (tid & 7) << 3;

  f32x4 acc[4][4] = {};

  for (int k0 = 0; k0 < 1024; k0 += 64) {
#pragma unroll
    for (int i = 0; i < 4; ++i) {
      const int r = trow + i * 32;
      gload_lds16(A + (size_t)(bm + r) * 1024 + k0 + tcol, sA + r * 64 + tcol);
      gload_lds16(W + (size_t)(bn + r) * 1024 + k0 + tcol, sB + r * 64 + tcol);
    }
    __syncthreads();

    bf16x8 af[4][2], bfr[4][2];
#pragma unroll
    for (int mi = 0; mi < 4; ++mi) {
      af[mi][0]  = *reinterpret_cast<const bf16x8*>(sA + (wr + mi * 16 + lrow) * 64 + lk8);
      af[mi][1]  = *reinterpret_cast<const bf16x8*>(sA + (wr + mi * 16 + lrow) * 64 + 32 + lk8);
      bfr[mi][0] = *reinterpret_cast<const bf16x8*>(sB + (wc + mi * 16 + lrow) * 64 + lk8);
      bfr[mi][1] = *reinterpret_cast<const bf16x8*>(sB + (wc + mi * 16 + lrow) * 64 + 32 + lk8);
    }
#pragma unroll
    for (int mi = 0; mi < 4; ++mi)
#pragma unroll
      for (int ni = 0; ni < 4; ++ni) {
        acc[mi][ni] = __builtin_amdgcn_mfma_f32_16x16x32_bf16(af[mi][0], bfr[ni][0], acc[mi][ni], 0, 0, 0);
        acc[mi][ni] = __builtin_amdgcn_mfma_f32_16x16x32_bf16(af[mi][1], bfr[ni][1], acc[mi][ni], 0, 0, 0);
      }
    __syncthreads();
  }

#pragma unroll
  for (int mi = 0; mi < 4; ++mi)
#pragma unroll
    for (int ni = 0; ni < 4; ++ni) {
      const int col = bn + wc + ni * 16 + lrow;          // global feature 0..2047
      const float bv = bias[col];
      const int d  = col & 63;
      const int hh = (col >> 6) & 15;
      // permuted sub-index for (t,lh,e) from d
      const size_t doff = (size_t)((d >> 4) * 2 + ((d >> 3) & 1)) * 256 + (d & 7);
#pragma unroll
      for (int j = 0; j < 4; ++j) {
        const int row = bm + wr + mi * 16 + ((lane >> 4) << 2) + j;  // token 0..8191
        const int bb  = row >> 11;
        const int tok = row & (TT - 1);
        const size_t idx = (size_t)(bb * NH + hh) * BH_STRIDE
                         + (size_t)(tok >> 5) * 2048 + doff + (size_t)(tok & 31) * 8;
        dst[idx] = __float2bfloat16((acc[mi][ni][j] + bv) * scale);
      }
    }
}

// ---- fused QK^T + softmax (no-max), 32x32 MFMA, permuted coalesced Q/K loads ----
// grid (16, 64): x = q-tile of 128 rows (32/wave), y = b*16+h.
__global__ __launch_bounds__(256, 4) void attn2_k(
    const bf16* __restrict__ Qp, const bf16* __restrict__ Kp, float* __restrict__ attn)
{
  const int tid  = threadIdx.x;
  const int lane = tid & 63;
  const int wave = tid >> 6;
  const int l31  = lane & 31;
  const int lh   = lane >> 5;
  const int bh   = blockIdx.y;       // b*16+h
  const int q0   = blockIdx.x * 128 + wave * 32;
  const int tc   = blockIdx.x * 4 + wave;   // q token-chunk

  // A fragment (Q): 1KB-coalesced loads from permuted layout
  const bf16* qb = Qp + (size_t)bh * BH_STRIDE + (size_t)tc * 2048 + lh * 256 + l31 * 8;
  bf16x8 aq[4];
#pragma unroll
  for (int t = 0; t < 4; ++t)
    aq[t] = *reinterpret_cast<const bf16x8*>(qb + t * 512);

  // B fragment (K^T): linear streaming through permuted K chunks
  const bf16* kb = Kp + (size_t)bh * BH_STRIDE + lh * 256 + l31 * 8;

  float s[16];
#pragma unroll
  for (int r = 0; r < 16; ++r) s[r] = 0.f;

  // ---- pass 1: row sums of exp2(S) ----
  for (int nc = 0; nc < 64; ++nc) {
    const bf16* kp = kb + (size_t)nc * 2048;
    bf16x8 bk0 = *reinterpret_cast<const bf16x8*>(kp);
    bf16x8 bk1 = *reinterpret_cast<const bf16x8*>(kp + 512);
    bf16x8 bk2 = *reinterpret_cast<const bf16x8*>(kp + 1024);
    bf16x8 bk3 = *reinterpret_cast<const bf16x8*>(kp + 1536);
    f32x16 acc = {};
    acc = __builtin_amdgcn_mfma_f32_32x32x16_bf16(aq[0], bk0, acc, 0, 0, 0);
    acc = __builtin_amdgcn_mfma_f32_32x32x16_bf16(aq[1], bk1, acc, 0, 0, 0);
    acc = __builtin_amdgcn_mfma_f32_32x32x16_bf16(aq[2], bk2, acc, 0, 0, 0);
    acc = __builtin_amdgcn_mfma_f32_32x32x16_bf16(aq[3], bk3, acc, 0, 0, 0);
#pragma unroll
    for (int r = 0; r < 16; ++r) s[r] += __builtin_amdgcn_exp2f(acc[r]);
  }

  // ---- merge partial sums across the 32 lanes sharing each row; invert ----
#pragma unroll
  for (int r = 0; r < 16; ++r) {
    float sr = s[r];
    sr += __shfl_xor(sr, 1);
    sr += __shfl_xor(sr, 2);
    sr += __shfl_xor(sr, 4);
    sr += __shfl_xor(sr, 8);
    sr += __shfl_xor(sr, 16);
    s[r] = 1.0f / sr;
  }

  // D layout: col = n0 + l31, row = q0 + (r&3) + 8*(r>>2) + 4*lh
  float* obase = attn + ((size_t)bh * TT + q0 + 4 * lh) * TT + l31;

  // ---- pass 2: recompute S, write normalized softmax ----
  for (int nc = 0; nc < 64; ++nc) {
    const bf16* kp = kb + (size_t)nc * 2048;
    bf16x8 bk0 = *reinterpret_cast<const bf16x8*>(kp);
    bf16x8 bk1 = *reinterpret_cast<const bf16x8*>(kp + 512);
    bf16x8 bk2 = *reinterpret_cast<const bf16x8*>(kp + 1024);
    bf16x8 bk3 = *reinterpret_cast<const bf16x8*>(kp + 1536);
    f32x16 acc = {};
    acc = __builtin_amdgcn_mfma_f32_32x32x16_bf16(aq[0], bk0, acc, 0, 0, 0);
    acc = __builtin_amdgcn_mfma_f32_32x32x16_bf16(aq[1], bk1, acc, 0, 0, 0);
    acc = __builtin_amdgcn_mfma_f32_32x32x16_bf16(aq[2], bk2, acc, 0, 0, 0);
    acc = __builtin_amdgcn_mfma_f32_32x32x16_bf16(aq[3], bk3, acc, 0, 0, 0);
#pragma unroll
    for (int r = 0; r < 16; ++r) {
      const float p = __builtin_amdgcn_exp2f(acc[r]) * s[r];
      __builtin_nontemporal_store(p, obase + (size_t)((r & 3) + 8 * (r >> 2)) * TT + nc * 32);
    }
  }
}

extern "C" void kernel_launch(void* const* d_in, const int* in_sizes, int n_in,
                              void* d_out, int out_size, void* d_ws, size_t ws_size,
                              hipStream_t stream) {
  // inputs: v,k,q, wq_w,wq_b, wk_w,wk_b, wv_w,wv_b, dense_w,dense_b, fc_w,fc_b
  const float* k_in = (const float*)d_in[1];
  const float* q_in = (const float*)d_in[2];
  const float* wq_w = (const float*)d_in[3];
  const float* wq_b = (const float*)d_in[4];
  const float* wk_w = (const float*)d_in[5];
  const float* wk_b = (const float*)d_in[6];
  float* out = (float*)d_out;

  // ws layout (bf16): qbf,kbf [8192x1024], w2 [2048x1024], Qp,Kp permuted [8192x1024]
  bf16* qbf  = (bf16*)d_ws;
  bf16* kbf  = qbf  + (size_t)NTOK * DM;
  bf16* w2   = kbf  + (size_t)NTOK * DM;     // wq rows then wk rows
  bf16* Qp   = w2   + (size_t)2 * DM * DM;
  bf16* Kp   = Qp   + (size_t)NTOK * DM;

  const int prep_blocks = (2 * N4_QK + 2 * N4_W + N4_ONES) / 256;  // 18440
  prep_k<<<prep_blocks, 256, 0, stream>>>(q_in, k_in, wq_w, wk_w, qbf, out);

  gemm_qk<<<1024, 256, 0, stream>>>(qbf, kbf, w2, wq_b, wk_b, Qp, Kp);

  dim3 ag(TT / 128, 4 * NH);
  attn2_k<<<ag, 256, 0, stream>>>(Qp, Kp, out + 8192);
}